// Round 1
// 3875.042 us; speedup vs baseline: 1.1115x; 1.1115x over previous
//
#include <hip/hip_runtime.h>

#define SS 2048
#define BATCH 512
#define NB 2          // batch elements per block
#define NT 512        // threads per block: 64 j * 8 ko

// ---------- fast fp32 helpers ----------
__device__ __forceinline__ float fast_rcp(float a) { return __builtin_amdgcn_rcpf(a); }
__device__ __forceinline__ float fast_exp2(float a) { return __builtin_amdgcn_exp2f(a); }

// ---------- DPP add (quad xor1 / xor2, row_half_mirror) ----------
template <int CTRL>
__device__ __forceinline__ float dpp_add(float v) {
  const int sh = __builtin_amdgcn_update_dpp(0, __float_as_int(v), CTRL, 0xf, 0xf, true);
  return v + __int_as_float(sh);
}

// ---------- DPP mov (quad_perm broadcast) ----------
template <int CTRL>
__device__ __forceinline__ float dpp_mov(float v) {
  return __int_as_float(__builtin_amdgcn_update_dpp(0, __float_as_int(v), CTRL, 0xf, 0xf, true));
}

// ---------- partial matvec over this thread's 8-wide K slice ----------
__device__ __forceinline__ void mv8(const float (&w)[4][8], const float* hsrc,
                                    float (&acc)[4]) {
  const float4 a = *(const float4*)(hsrc);
  const float4 b = *(const float4*)(hsrc + 4);
  const float hv[8] = {a.x, a.y, a.z, a.w, b.x, b.y, b.z, b.w};
#pragma unroll
  for (int g = 0; g < 4; ++g) {
    float s = acc[g];
#pragma unroll
    for (int kk = 0; kk < 8; ++kk) s = fmaf(w[g][kk], hv[kk], s);
    acc[g] = s;
  }
}

// 2-stage DPP quad reduce (4 gates), select lane's gate, then finish the
// cross-quad (xor4) sum with DPP row_half_mirror: lane q pairs with 7-q.
// Upper-quad lanes select gate 3-(ko&3), so both mirror partners carry the
// SAME gate -> the two addends are bitwise identical to the old xor4 pair.
// All DS-pipe swizzles eliminated; pure VALU.
__device__ __forceinline__ float redsel(float (&a)[4], bool kb0, bool kb1) {
#pragma unroll
  for (int g = 0; g < 4; ++g) {
    a[g] = dpp_add<0xB1>(a[g]);   // quad_perm(1,0,3,2) = xor1
    a[g] = dpp_add<0x4E>(a[g]);   // quad_perm(2,3,0,1) = xor2
  }
  const float s01 = kb0 ? a[1] : a[0];
  const float s23 = kb0 ? a[3] : a[2];
  float s = kb1 ? s23 : s01;            // gate gsel (see kernel init)
  s = dpp_add<0x141>(s);                // row_half_mirror -> full K sum
  return s;
}

// Branchless activation (per-lane consts) + quad-level gate broadcast +
// c/h update. Broadcast values are correct in quad0 (lanes hold gates
// i,f,g,o in order); quad1 lanes produce permuted garbage, but only lane
// ko==0 (in quad0) ever writes h, and c of lanes 4..7 feeds nothing.
__device__ __forceinline__ float gate_finish(float pre, float kact, float aact,
                                             float bact, float& c) {
  const float e = fast_exp2(kact * pre);
  const float r = fast_rcp(1.0f + e);
  const float a = fmaf(aact, r, bact);
  // broadcast the 4 gate values within the quad (VALU DPP, no DS pipe)
  const float vi = dpp_mov<0x00>(a);    // quad_perm(0,0,0,0): gate i
  const float vf = dpp_mov<0x55>(a);    // quad_perm(1,1,1,1): gate f
  const float vg = dpp_mov<0xAA>(a);    // quad_perm(2,2,2,2): gate g
  const float vo = dpp_mov<0xFF>(a);    // quad_perm(3,3,3,3): gate o
  c = fmaf(vf, c, vi * vg);
  const float te = fast_exp2(2.8853900817779268f * c);   // tanh(c)
  const float tr = fast_rcp(1.0f + te);
  const float t = vo * tr;
  return fmaf(-2.0f, t, vo);            // o * tanh(c)
}

// One timestep. Ping-pong parity CUR -> NXT; 2 barriers (hazard analysis
// unchanged: every conflicting write/read pair is separated by >= 2 of the
// per-step barriers).
template <int CUR, int NXT>
__device__ __forceinline__ void lstm_step(
    float (&hb)[2][3][NB][64],
    const float (&whh0)[4][8], const float (&wih1)[4][8],
    const float (&whh1)[4][8], const float (&wih2)[4][8],
    const float (&whh2)[4][8],
    const float (&wi0l)[4],   // per-lane Wih0 row (gate gsel)
    float b0l, float b1l, float b2l,          // per-lane biases
    float kact, float aact, float bact,       // per-lane activation consts
    float (&c0)[NB], float (&c1)[NB], float (&c2)[NB],
    const float (&xin)[NB][4], int j, int ko, int k0,
    bool kb0, bool kb1, bool wr) {
  float p0[NB][4], p1[NB][4];
  // ---- S1: barrier-safe old-h matvecs ----
#pragma unroll
  for (int b = 0; b < NB; ++b) {
#pragma unroll
    for (int g = 0; g < 4; ++g) { p0[b][g] = 0.f; p1[b][g] = 0.f; }
    mv8(whh0, &hb[CUR][0][b][k0], p0[b]);
    mv8(whh1, &hb[CUR][1][b][k0], p1[b]);
  }
  // ---- finish layer 0 (adds per-lane x-projection + bias) ----
#pragma unroll
  for (int b = 0; b < NB; ++b) {
    float s = redsel(p0[b], kb0, kb1);
    float d = b0l;
#pragma unroll
    for (int f2 = 0; f2 < 4; ++f2) d = fmaf(wi0l[f2], xin[b][f2], d);
    const float hn = gate_finish(s + d, kact, aact, bact, c0[b]);
    if (wr) hb[NXT][0][b][j] = hn;
  }
  __syncthreads();  // barrier A
  // ---- layer 1 ----
#pragma unroll
  for (int b = 0; b < NB; ++b) {
    mv8(wih1, &hb[NXT][0][b][k0], p1[b]);
    const float hn = gate_finish(redsel(p1[b], kb0, kb1) + b1l, kact, aact, bact, c1[b]);
    if (wr) hb[NXT][1][b][j] = hn;
  }
  __syncthreads();  // barrier B
  // ---- layer 2 ----
#pragma unroll
  for (int b = 0; b < NB; ++b) {
    float p2[4] = {0.f, 0.f, 0.f, 0.f};
    mv8(wih2, &hb[NXT][1][b][k0], p2);
    mv8(whh2, &hb[CUR][2][b][k0], p2);
    const float hn = gate_finish(redsel(p2, kb0, kb1) + b2l, kact, aact, bact, c2[b]);
    if (wr) hb[NXT][2][b][j] = hn;
  }
}

__global__ void __launch_bounds__(NT, 2)
lstm3_kernel(const float* __restrict__ x,
             const float* __restrict__ Wih0, const float* __restrict__ Whh0,
             const float* __restrict__ bih0, const float* __restrict__ bhh0,
             const float* __restrict__ Wih1, const float* __restrict__ Whh1,
             const float* __restrict__ bih1, const float* __restrict__ bhh1,
             const float* __restrict__ Wih2, const float* __restrict__ Whh2,
             const float* __restrict__ bih2, const float* __restrict__ bhh2,
             const float* __restrict__ fcw, const float* __restrict__ fcb,
             float* __restrict__ out) {
  __shared__ float hb[2][3][NB][64];  // [parity][layer][b][k], 3 KB
  const int tid = threadIdx.x;
  const int j = tid >> 3;       // hidden unit 0..63
  const int ko = tid & 7;       // K-octant (lane bits 0..2)
  const int k0 = ko << 3;
  const int bbase = blockIdx.x * NB;
  // Gate selected by this lane after the quad reduce. Upper quad (ko&4)
  // takes the REVERSED gate order so that row_half_mirror (lane q <-> 7-q)
  // pairs identical gates for the cross-quad sum.
  const int gl = (ko & 4) ? (3 - (ko & 3)) : (ko & 3);
  const bool kb0 = (gl & 1) != 0;
  const bool kb1 = (gl & 2) != 0;
  const bool wr = (ko == 0);

  // register-resident weights: 4 gate-rows x 8-wide K slice per matrix
  float whh0[4][8], wih1[4][8], whh1[4][8], wih2[4][8], whh2[4][8];
#pragma unroll
  for (int g = 0; g < 4; ++g) {
    const int r = (g << 6) + j;   // PyTorch gate-order rows: i,f,g,o
    const int ro = (r << 6) + k0;
    *(float4*)&whh0[g][0] = *(const float4*)&Whh0[ro];
    *(float4*)&whh0[g][4] = *(const float4*)&Whh0[ro + 4];
    *(float4*)&wih1[g][0] = *(const float4*)&Wih1[ro];
    *(float4*)&wih1[g][4] = *(const float4*)&Wih1[ro + 4];
    *(float4*)&whh1[g][0] = *(const float4*)&Whh1[ro];
    *(float4*)&whh1[g][4] = *(const float4*)&Whh1[ro + 4];
    *(float4*)&wih2[g][0] = *(const float4*)&Wih2[ro];
    *(float4*)&wih2[g][4] = *(const float4*)&Wih2[ro + 4];
    *(float4*)&whh2[g][0] = *(const float4*)&Whh2[ro];
    *(float4*)&whh2[g][4] = *(const float4*)&Whh2[ro + 4];
  }

  // per-lane gate-specific constants (gate = gl)
  const int rl = (gl << 6) + j;
  const float b0l = bih0[rl] + bhh0[rl];
  const float b1l = bih1[rl] + bhh1[rl];
  const float b2l = bih2[rl] + bhh2[rl];
  float wi0l[4];
  {
    const float4 w0 = *(const float4*)&Wih0[rl * 4];
    wi0l[0] = w0.x; wi0l[1] = w0.y; wi0l[2] = w0.z; wi0l[3] = w0.w;
  }
  const bool isg = (gl == 2);
  const float kact = isg ? 2.8853900817779268f : -1.4426950408889634f;
  const float aact = isg ? -2.0f : 1.0f;
  const float bact = isg ? 1.0f : 0.0f;

  float c0[NB], c1[NB], c2[NB];
#pragma unroll
  for (int b = 0; b < NB; ++b) { c0[b] = 0.f; c1[b] = 0.f; c2[b] = 0.f; }

  {  // zero both parities of h
    float* p = &hb[0][0][0][0];
    for (int i = tid; i < 2 * 3 * NB * 64; i += NT) p[i] = 0.f;
  }

  // x prefetch (full 4-vector per batch elem, double-buffered)
  float xc[NB][4], xn[NB][4];
#pragma unroll
  for (int b = 0; b < NB; ++b) {
    const float4 v = *(const float4*)&x[(size_t)(bbase + b) * SS * 4];
    xc[b][0] = v.x; xc[b][1] = v.y; xc[b][2] = v.z; xc[b][3] = v.w;
  }
  __syncthreads();

#pragma unroll 1
  for (int t = 0; t < SS; t += 2) {
#pragma unroll
    for (int b = 0; b < NB; ++b) {
      const float4 v = *(const float4*)&x[((size_t)(bbase + b) * SS + (t + 1)) * 4];
      xn[b][0] = v.x; xn[b][1] = v.y; xn[b][2] = v.z; xn[b][3] = v.w;
    }
    lstm_step<0, 1>(hb, whh0, wih1, whh1, wih2, whh2, wi0l, b0l, b1l, b2l,
                    kact, aact, bact, c0, c1, c2, xc, j, ko, k0, kb0, kb1, wr);
    const int tp = (t + 2 < SS) ? (t + 2) : (SS - 1);
#pragma unroll
    for (int b = 0; b < NB; ++b) {
      const float4 v = *(const float4*)&x[((size_t)(bbase + b) * SS + tp) * 4];
      xc[b][0] = v.x; xc[b][1] = v.y; xc[b][2] = v.z; xc[b][3] = v.w;
    }
    lstm_step<1, 0>(hb, whh0, wih1, whh1, wih2, whh2, wi0l, b0l, b1l, b2l,
                    kact, aact, bact, c0, c1, c2, xn, j, ko, k0, kb0, kb1, wr);
  }
  __syncthreads();  // publish final h2 (parity 0 after t=2047)

  // fc: out[b][o] = fc_b[o] + sum_j fc_w[o][j] * h2_last[b][j]
  if (tid < NB * 2) {
    const int b = tid >> 1, o = tid & 1;
    float s = fcb[o];
#pragma unroll
    for (int jj = 0; jj < 64; ++jj)
      s = fmaf(fcw[o * 64 + jj], hb[0][2][b][jj], s);
    out[(bbase + b) * 2 + o] = s;
  }
}

extern "C" void kernel_launch(void* const* d_in, const int* in_sizes, int n_in,
                              void* d_out, int out_size, void* d_ws, size_t ws_size,
                              hipStream_t stream) {
  const float* x    = (const float*)d_in[0];
  const float* Wih0 = (const float*)d_in[1];
  const float* Whh0 = (const float*)d_in[2];
  const float* bih0 = (const float*)d_in[3];
  const float* bhh0 = (const float*)d_in[4];
  const float* Wih1 = (const float*)d_in[5];
  const float* Whh1 = (const float*)d_in[6];
  const float* bih1 = (const float*)d_in[7];
  const float* bhh1 = (const float*)d_in[8];
  const float* Wih2 = (const float*)d_in[9];
  const float* Whh2 = (const float*)d_in[10];
  const float* bih2 = (const float*)d_in[11];
  const float* bhh2 = (const float*)d_in[12];
  const float* fcw  = (const float*)d_in[13];
  const float* fcb  = (const float*)d_in[14];
  float* out = (float*)d_out;

  lstm3_kernel<<<dim3(BATCH / NB), dim3(NT), 0, stream>>>(
      x, Wih0, Whh0, bih0, bhh0, Wih1, Whh1, bih1, bhh1,
      Wih2, Whh2, bih2, bhh2, fcw, fcb, out);
}